// Round 8
// baseline (318.564 us; speedup 1.0000x reference)
//
#include <hip/hip_runtime.h>
#include <hip/hip_bf16.h>
#include <stdint.h>

typedef unsigned int uint32;
typedef unsigned short u16;
typedef __attribute__((ext_vector_type(4))) float f32x4;
typedef __attribute__((ext_vector_type(16))) float f32x16;
typedef __attribute__((ext_vector_type(8))) __bf16 bf16x8;
typedef __attribute__((ext_vector_type(8))) short i16x8;
typedef __attribute__((ext_vector_type(4))) short i16x4;
typedef __attribute__((ext_vector_type(4))) uint32 u32x4;

#define DEVINL static __device__ __forceinline__

DEVINL u16 f2bf(float f){
  uint32 u = __builtin_bit_cast(uint32, f);
  return (u16)((u + 0x7fffu + ((u >> 16) & 1u)) >> 16);  // RNE
}

DEVINL uint32 cvtpk(float lo, float hi){
  uint32 r;
  asm("v_cvt_pk_bf16_f32 %0, %1, %2" : "=v"(r) : "v"(lo), "v"(hi));
  return r;
}

// vdst.hi32lanes <-> vsrc.lo32lanes
DEVINL void permswap(uint32 &a, uint32 &b){
  asm volatile("s_nop 1\n\tv_permlane32_swap_b32 %0, %1" : "+v"(a), "+v"(b));
}

DEVINL f32x4 mfma16(bf16x8 a, bf16x8 b, f32x4 c){
  return __builtin_amdgcn_mfma_f32_16x16x32_bf16(a, b, c, 0, 0, 0);
}
DEVINL f32x16 mfma32(bf16x8 a, bf16x8 b, f32x16 c){
  return __builtin_amdgcn_mfma_f32_32x32x16_bf16(a, b, c, 0, 0, 0);
}
DEVINL f32x16 zero16(){
  f32x16 z;
  #pragma unroll
  for (int r = 0; r < 16; ++r) z[r] = 0.f;
  return z;
}

// async global->LDS, 16B per lane; LDS dest is wave-uniform base + lane*16
DEVINL void gload16(const u16* g, u16* l){
  __builtin_amdgcn_global_load_lds(
      (const __attribute__((address_space(1))) uint32*)g,
      (__attribute__((address_space(3))) uint32*)l, 16, 0, 0);
}

static constexpr size_t ISTR = 2048 * 64;   // elems per attention instance
static constexpr float QSCALE = 0.18033688011112042f;  // log2(e)/8 folded into Q
static constexpr int LDA = 40;              // padded A-tile stride (VALU-written)

// ---------------- weight f32 -> bf16 (all four in one dispatch) ----------------
__global__ void cvt_w4(const float* __restrict__ s0, const float* __restrict__ s1,
                       const float* __restrict__ s2, const float* __restrict__ s3,
                       u16* __restrict__ d0, u16* __restrict__ d1,
                       u16* __restrict__ d2, u16* __restrict__ d3, int n4){
  const int wsel = blockIdx.y;
  const float* src = wsel == 0 ? s0 : wsel == 1 ? s1 : wsel == 2 ? s2 : s3;
  u16* dst = wsel == 0 ? d0 : wsel == 1 ? d1 : wsel == 2 ? d2 : d3;
  int i = blockIdx.x * 256 + threadIdx.x;
  if (i < n4){
    f32x4 v = *(const f32x4*)(src + (size_t)i * 4);
    u16 o[4];
    #pragma unroll
    for (int j = 0; j < 4; ++j) o[j] = f2bf(v[j]);
    *(i16x4*)(dst + (size_t)i * 4) = *(const i16x4*)o;
  }
}

// ---------------- fused QKV projection GEMM ----------------
// 1D grid 2304, XCD-clustered remap: nid=(id&7)*288+(id>>3); nid = sect*768 + rowtile*6 + col.
// => the 6 col-tile blocks sharing one A row-panel are adjacent on the SAME XCD (A L2-resident).
__global__ __launch_bounds__(256) void qkv_fused(
    const float* __restrict__ X0, const float* __restrict__ X1, const float* __restrict__ X2,
    const u16* __restrict__ W0, const u16* __restrict__ W1, const u16* __restrict__ W2,
    const float* __restrict__ b0, const float* __restrict__ b1, const float* __restrict__ b2,
    u16* __restrict__ Y0, u16* __restrict__ Y1, u16* __restrict__ Y2)
{
  __shared__ u16 As[2][128 * LDA];
  __shared__ u16 Bs[2][128 * 32];
  const int tid = threadIdx.x;
  const int l = tid & 63, w = tid >> 6;
  const int l15 = l & 15, lh = l >> 4;
  const int wr = w >> 1, wc = w & 1;

  const int id = blockIdx.x;
  const int nid = (id & 7) * 288 + (id >> 3);   // 288 contiguous nids per XCD
  const int sect = nid / 768;
  const int rem = nid - sect * 768;
  const int rowtile = rem / 6;
  const int row0 = rowtile * 128, col0 = (rem - rowtile * 6) * 128;

  const float* X   = sect == 0 ? X0 : sect == 1 ? X1 : X2;
  const u16*   W   = sect == 0 ? W0 : sect == 1 ? W1 : W2;
  const float* bia_p = sect == 0 ? b0 : sect == 1 ? b1 : b2;
  u16*         Yg  = sect == 0 ? Y0 : sect == 1 ? Y1 : Y2;
  const float scale = sect == 0 ? QSCALE : 1.0f;
  const int tmode = (sect == 2) ? 1 : 0;

  // B staging: lane covers row gr = l>>2 (in 16-row group); source chunk pre-XORed so
  // LDS chunk c holds global chunk c ^ ((row>>1)&3)   [T2 / m173 both-sides swizzle]
  const int gr = l >> 2;
  const int gcx = ((l & 3) ^ ((gr >> 1) & 3)) * 8;
  const u16* wsrc0 = W + (size_t)(col0 + w * 32 + gr) * 768 + gcx;

  // A staging: thread t loads 16 f32 of row sr, writes 16 bf16 into padded tile
  const int sr = tid >> 1, sc = (tid & 1) * 16;
  const float* asrc = X + (size_t)(row0 + sr) * 768 + sc;

  f32x4 acc[4][4];
  #pragma unroll
  for (int i = 0; i < 4; ++i)
    #pragma unroll
    for (int j = 0; j < 4; ++j) acc[i][j] = f32x4{0.f, 0.f, 0.f, 0.f};

  auto STAGE_B = [&](int buf, int ks){
    const u16* ws = wsrc0 + ks * 32;
    gload16(ws,            &Bs[buf][(w * 32) * 32]);
    gload16(ws + 16 * 768, &Bs[buf][(w * 32 + 16) * 32]);
  };
  auto WRITE_A = [&](int buf, f32x4 ra0, f32x4 ra1, f32x4 ra2, f32x4 ra3){
    u32x4 w0 = { cvtpk(ra0[0], ra0[1]), cvtpk(ra0[2], ra0[3]),
                 cvtpk(ra1[0], ra1[1]), cvtpk(ra1[2], ra1[3]) };
    u32x4 w1 = { cvtpk(ra2[0], ra2[1]), cvtpk(ra2[2], ra2[3]),
                 cvtpk(ra3[0], ra3[1]), cvtpk(ra3[2], ra3[3]) };
    *(i16x8*)&As[buf][sr * LDA + sc]     = __builtin_bit_cast(i16x8, w0);
    *(i16x8*)&As[buf][sr * LDA + sc + 8] = __builtin_bit_cast(i16x8, w1);
  };

  // prologue: stage step 0
  {
    STAGE_B(0, 0);
    f32x4 ra0 = *(const f32x4*)(asrc);
    f32x4 ra1 = *(const f32x4*)(asrc + 4);
    f32x4 ra2 = *(const f32x4*)(asrc + 8);
    f32x4 ra3 = *(const f32x4*)(asrc + 12);
    WRITE_A(0, ra0, ra1, ra2, ra3);
  }
  asm volatile("s_waitcnt vmcnt(0)");
  __syncthreads();

  const int bxor = ((l15 >> 1) & 3) * 8;   // read-side XOR for B chunks
  int cur = 0;
  for (int ks = 0; ks < 24; ++ks) {
    const int nxt = cur ^ 1;
    f32x4 ra0, ra1, ra2, ra3;
    const bool has = ks < 23;
    if (has) {
      STAGE_B(nxt, ks + 1);
      const float* ap = asrc + (ks + 1) * 32;
      ra0 = *(const f32x4*)(ap);      ra1 = *(const f32x4*)(ap + 4);
      ra2 = *(const f32x4*)(ap + 8);  ra3 = *(const f32x4*)(ap + 12);
    }
    bf16x8 af[4], bfr[4];
    #pragma unroll
    for (int mi = 0; mi < 4; ++mi)
      af[mi] = *(const bf16x8*)&As[cur][(wr * 64 + mi * 16 + l15) * LDA + lh * 8];
    #pragma unroll
    for (int ni = 0; ni < 4; ++ni)
      bfr[ni] = *(const bf16x8*)&Bs[cur][(wc * 64 + ni * 16 + l15) * 32 + ((lh * 8) ^ bxor)];
    #pragma unroll
    for (int mi = 0; mi < 4; ++mi)
      #pragma unroll
      for (int ni = 0; ni < 4; ++ni)
        acc[mi][ni] = mfma16(af[mi], bfr[ni], acc[mi][ni]);
    if (has) WRITE_A(nxt, ra0, ra1, ra2, ra3);
    asm volatile("s_waitcnt vmcnt(0)");
    __syncthreads();
    cur = nxt;
  }

  // scatter epilogue: C layout col=lane&15, row=(lane>>4)*4+reg  [m89]
  #pragma unroll
  for (int ni = 0; ni < 4; ++ni) {
    const int e = col0 + wc * 64 + ni * 16 + l15;
    const int h = e >> 6, d = e & 63;
    const int grp = h >> 2, hg = h & 3;
    const int instB = (grp == 0) ? 0 : (grp == 1) ? 32 : 48;
    const float bia = bia_p[e];
    #pragma unroll
    for (int mi = 0; mi < 4; ++mi) {
      #pragma unroll
      for (int r = 0; r < 4; ++r) {
        const int row = row0 + wr * 64 + mi * 16 + lh * 4 + r;
        const int b = row >> 13, nn = row & 8191;
        const int p = nn & ((2048 << grp) - 1);
        if ((p & ((1 << grp) - 1)) != grp) continue;   // off dilation grid
        const int seg = nn >> (11 + grp);
        const int t = (p - grp) >> grp;
        const int inst = instB + ((b * (4 >> grp) + seg) << 2) + hg;
        const u16 val = f2bf((acc[mi][ni][r] + bia) * scale);
        if (tmode == 0) Yg[(size_t)inst * ISTR + (size_t)t * 64 + d] = val;
        else            Yg[(size_t)inst * ISTR + (size_t)d * 2048 + t] = val;
      }
    }
  }
}

// ---------------- dilated flash attention: 4 waves, LDS-staged K/V, split-K 2 ----------------
__global__ __launch_bounds__(256) void dil_attn(
    const u16* __restrict__ Qg, const u16* __restrict__ Kg,
    const u16* __restrict__ VgT, uint32* __restrict__ Op32, float* __restrict__ Ls)
{
  __shared__ u16 Kb[2][64 * 64];
  __shared__ u16 Vb[2][64 * 64];
  const int tid = threadIdx.x;
  const int w = tid >> 6, l = tid & 63;
  const int l31 = l & 31, hi = l >> 5;
  const int id = blockIdx.x;
  const int nid = (id & 7) * 224 + (id >> 3);
  const int inst = nid >> 5, rem = nid & 31;
  const int qb = rem >> 1, kh = rem & 1;
  const size_t ibase = (size_t)inst * ISTR;
  const int qbase = qb * 128 + w * 32;
  const int k0base = kh * 1024;

  const u16* qlane = Qg + ibase + (size_t)(qbase + l31) * 64 + hi * 8;
  const bf16x8 qf0 = *(const bf16x8*)(qlane);
  const bf16x8 qf1 = *(const bf16x8*)(qlane + 16);
  const bf16x8 qf2 = *(const bf16x8*)(qlane + 32);
  const bf16x8 qf3 = *(const bf16x8*)(qlane + 48);

  const int srow = l >> 3;
  const int scol = ((l & 7) ^ (srow & 7)) << 3;
  const u16* kgs = Kg  + ibase + (size_t)srow * 64 + scol;
  const u16* vgs = VgT + ibase + (size_t)srow * 2048 + scol;

  f32x16 acc0 = zero16(), acc1 = zero16(), rs = zero16();
  const int sxor = (l31 & 7) << 3;
  const bf16x8 ones = __builtin_bit_cast(bf16x8,
      u32x4{0x3F803F80u, 0x3F803F80u, 0x3F803F80u, 0x3F803F80u});

  auto STAGE = [&](int buf, int k0){
    #pragma unroll
    for (int q = 0; q < 2; ++q){
      const int rb = w * 16 + q * 8;
      gload16(kgs + (size_t)(k0 + rb) * 64, &Kb[buf][rb * 64]);
      gload16(vgs + (size_t)rb * 2048 + k0, &Vb[buf][rb * 64]);
    }
  };

  STAGE(0, k0base);
  asm volatile("s_waitcnt vmcnt(0)");
  __syncthreads();

  int cur = 0;
  for (int step = 0; step < 16; ++step) {
    if (step < 15) STAGE(cur ^ 1, k0base + ((step + 1) << 6));
    const u16* kt = &Kb[cur][0];
    const u16* vt = &Vb[cur][0];
    #pragma unroll
    for (int s = 0; s < 2; ++s) {
      const int ksub = s * 32;
      const int krow = (ksub + l31) * 64;
      bf16x8 kc0 = *(const bf16x8*)&kt[krow + ((hi * 8)      ^ sxor)];
      bf16x8 kc1 = *(const bf16x8*)&kt[krow + ((16 + hi * 8) ^ sxor)];
      bf16x8 kc2 = *(const bf16x8*)&kt[krow + ((32 + hi * 8) ^ sxor)];
      bf16x8 kc3 = *(const bf16x8*)&kt[krow + ((48 + hi * 8) ^ sxor)];

      f32x16 sT = zero16();
      sT = mfma32(kc0, qf0, sT);
      sT = mfma32(kc1, qf1, sT);
      sT = mfma32(kc2, qf2, sT);
      sT = mfma32(kc3, qf3, sT);

      #pragma unroll
      for (int r = 0; r < 16; ++r) sT[r] = __builtin_amdgcn_exp2f(sT[r]);

      uint32 cw0 = cvtpk(sT[0],  sT[1]),  cw1 = cvtpk(sT[2],  sT[3]);
      uint32 cw2 = cvtpk(sT[4],  sT[5]),  cw3 = cvtpk(sT[6],  sT[7]);
      uint32 cw4 = cvtpk(sT[8],  sT[9]),  cw5 = cvtpk(sT[10], sT[11]);
      uint32 cw6 = cvtpk(sT[12], sT[13]), cw7 = cvtpk(sT[14], sT[15]);
      permswap(cw0, cw2); permswap(cw1, cw3);
      permswap(cw4, cw6); permswap(cw5, cw7);
      bf16x8 pa0 = __builtin_bit_cast(bf16x8, u32x4{cw0, cw1, cw2, cw3});
      bf16x8 pa1 = __builtin_bit_cast(bf16x8, u32x4{cw4, cw5, cw6, cw7});

      const int vr0 = l31 * 64, vr1 = (l31 + 32) * 64;
      bf16x8 v00 = *(const bf16x8*)&vt[vr0 + ((ksub + hi * 8)      ^ sxor)];
      bf16x8 v01 = *(const bf16x8*)&vt[vr0 + ((ksub + 16 + hi * 8) ^ sxor)];
      bf16x8 v10 = *(const bf16x8*)&vt[vr1 + ((ksub + hi * 8)      ^ sxor)];
      bf16x8 v11 = *(const bf16x8*)&vt[vr1 + ((ksub + 16 + hi * 8) ^ sxor)];

      rs   = mfma32(pa0, ones, rs);
      rs   = mfma32(pa1, ones, rs);
      acc0 = mfma32(pa0, v00, acc0);
      acc0 = mfma32(pa1, v01, acc0);
      acc1 = mfma32(pa0, v10, acc1);
      acc1 = mfma32(pa1, v11, acc1);
    }
    asm volatile("s_waitcnt vmcnt(0)");
    __syncthreads();
    cur ^= 1;
  }

  if (l31 == 0) {
    float* lsp = Ls + ((size_t)kh * 56 + inst) * 2048 + qbase;
    #pragma unroll
    for (int r = 0; r < 16; ++r) {
      const int qrow = (r & 3) + 8 * (r >> 2) + 4 * hi;
      lsp[qrow] = rs[r];
    }
  }
  uint32* op = Op32 + (size_t)kh * (56u * 2048u * 32u)
                    + ((size_t)inst * 2048 + qbase) * 32 + l31;
  #pragma unroll
  for (int r = 0; r < 16; ++r) {
    const int qrow = (r & 3) + 8 * (r >> 2) + 4 * hi;
    op[(size_t)qrow * 32] = cvtpk(acc0[r], acc1[r]);
  }
}

// ---------------- gather + combine split-K + normalize + LayerNorm -> xln ----------------
__global__ __launch_bounds__(256) void ln_gather(
    const uint32* __restrict__ Op32, const float* __restrict__ Ls,
    const float* __restrict__ gamma, const float* __restrict__ beta,
    u16* __restrict__ xln)
{
  const int row = blockIdx.x;            // 0..16383
  const int b = row >> 13, nn = row & 8191;
  const int tid = threadIdx.x;
  const size_t KHOFF = 56u * 2048u * 32u;
  float v[3];
  #pragma unroll
  for (int j = 0; j < 3; ++j) {
    const int e = tid + j * 256;
    const int h = e >> 6, d = e & 63;
    const int grp = h >> 2, hg = h & 3;
    const int p = nn & ((2048 << grp) - 1);
    float val = 0.f;
    if ((p & ((1 << grp) - 1)) == grp) {
      const int seg = nn >> (11 + grp);
      const int instB = (grp == 0) ? 0 : (grp == 1) ? 32 : 48;
      const int inst = instB + ((b * (4 >> grp) + seg) << 2) + hg;
      const int t = (p - grp) >> grp;
      const size_t wbase = ((size_t)inst * 2048 + t) * 32 + (d & 31);
      const uint32 w0 = Op32[wbase];
      const uint32 w1 = Op32[wbase + KHOFF];
      const float o0 = __builtin_bit_cast(float, d < 32 ? (w0 << 16) : (w0 & 0xFFFF0000u));
      const float o1 = __builtin_bit_cast(float, d < 32 ? (w1 << 16) : (w1 & 0xFFFF0000u));
      const float s = Ls[(size_t)inst * 2048 + t] + Ls[(size_t)(56 * 2048) + inst * 2048 + t];
      val = (o0 + o1) * (1.0f / (3.0f * s));
    }
    v[j] = val;
  }
  float s = v[0] + v[1] + v[2];
  float q = v[0]*v[0] + v[1]*v[1] + v[2]*v[2];
  #pragma unroll
  for (int off = 1; off < 64; off <<= 1) { s += __shfl_xor(s, off); q += __shfl_xor(q, off); }
  __shared__ float red[8];
  const int w = tid >> 6, l = tid & 63;
  if (l == 0) { red[w] = s; red[4 + w] = q; }
  __syncthreads();
  s = red[0] + red[1] + red[2] + red[3];
  q = red[4] + red[5] + red[6] + red[7];
  const float mu = s * (1.f / 768.f);
  const float var = q * (1.f / 768.f) - mu * mu;
  const float rs = rsqrtf(var + 1e-5f);
  #pragma unroll
  for (int j = 0; j < 3; ++j) {
    const int e = tid + j * 256;
    xln[(size_t)row * 768 + e] = f2bf((v[j] - mu) * rs * gamma[e] + beta[e]);
  }
}

// ---------------- output projection GEMM (bf16 A and B via swizzled global_load_lds) ----------------
// 1D grid 768, XCD-clustered remap: nid=(id&7)*96+(id>>3); nid = rowtile*6 + col.
__global__ __launch_bounds__(256) void out_gemm(
    const u16* __restrict__ Xb, const u16* __restrict__ W,
    const float* __restrict__ bias, float* __restrict__ out)
{
  __shared__ u16 As[2][128 * 32];
  __shared__ u16 Bs[2][128 * 32];
  const int tid = threadIdx.x;
  const int l = tid & 63, w = tid >> 6;
  const int l15 = l & 15, lh = l >> 4;
  const int wr = w >> 1, wc = w & 1;

  const int id = blockIdx.x;
  const int nid = (id & 7) * 96 + (id >> 3);
  const int rowtile = nid / 6;
  const int row0 = rowtile * 128, col0 = (nid - rowtile * 6) * 128;

  const int gr = l >> 2;
  const int gcx = ((l & 3) ^ ((gr >> 1) & 3)) * 8;   // pre-swizzled source chunk [T2]
  const u16* asrc0 = Xb + (size_t)(row0 + w * 32 + gr) * 768 + gcx;
  const u16* wsrc0 = W  + (size_t)(col0 + w * 32 + gr) * 768 + gcx;

  f32x4 acc[4][4];
  #pragma unroll
  for (int i = 0; i < 4; ++i)
    #pragma unroll
    for (int j = 0; j < 4; ++j) acc[i][j] = f32x4{0.f, 0.f, 0.f, 0.f};

  auto STAGE = [&](int buf, int ks){
    const u16* as = asrc0 + ks * 32;
    const u16* ws = wsrc0 + ks * 32;
    gload16(as,            &As[buf][(w * 32) * 32]);
    gload16(as + 16 * 768, &As[buf][(w * 32 + 16) * 32]);
    gload16(ws,            &Bs[buf][(w * 32) * 32]);
    gload16(ws + 16 * 768, &Bs[buf][(w * 32 + 16) * 32]);
  };

  STAGE(0, 0);
  asm volatile("s_waitcnt vmcnt(0)");
  __syncthreads();

  const int bxor = ((l15 >> 1) & 3) * 8;   // read-side XOR
  int cur = 0;
  for (int ks = 0; ks < 24; ++ks) {
    const int nxt = cur ^ 1;
    if (ks < 23) STAGE(nxt, ks + 1);
    bf16x8 af[4], bfr[4];
    #pragma unroll
    for (int mi = 0; mi < 4; ++mi)
      af[mi] = *(const bf16x8*)&As[cur][(wr * 64 + mi * 16 + l15) * 32 + ((lh * 8) ^ bxor)];
    #pragma unroll
    for (int ni = 0; ni < 4; ++ni)
      bfr[ni] = *(const bf16x8*)&Bs[cur][(wc * 64 + ni * 16 + l15) * 32 + ((lh * 8) ^ bxor)];
    #pragma unroll
    for (int mi = 0; mi < 4; ++mi)
      #pragma unroll
      for (int ni = 0; ni < 4; ++ni)
        acc[mi][ni] = mfma16(af[mi], bfr[ni], acc[mi][ni]);
    asm volatile("s_waitcnt vmcnt(0)");
    __syncthreads();
    cur = nxt;
  }

  #pragma unroll
  for (int ni = 0; ni < 4; ++ni) {
    const int e = col0 + wc * 64 + ni * 16 + l15;
    const float bia = bias[e];
    #pragma unroll
    for (int mi = 0; mi < 4; ++mi) {
      #pragma unroll
      for (int r = 0; r < 4; ++r) {
        const int row = row0 + wr * 64 + mi * 16 + lh * 4 + r;
        out[(size_t)row * 768 + e] = acc[mi][ni][r] + bia;
      }
    }
  }
}

extern "C" void kernel_launch(void* const* d_in, const int* in_sizes, int n_in,
                              void* d_out, int out_size, void* d_ws, size_t ws_size,
                              hipStream_t stream) {
  const float* query = (const float*)d_in[0];
  const float* key_  = (const float*)d_in[1];
  const float* value = (const float*)d_in[2];
  const float* Wq = (const float*)d_in[3];
  const float* bq = (const float*)d_in[4];
  const float* Wk = (const float*)d_in[5];
  const float* bk = (const float*)d_in[6];
  const float* Wv = (const float*)d_in[7];
  const float* bv = (const float*)d_in[8];
  const float* Wo = (const float*)d_in[9];
  const float* bo = (const float*)d_in[10];
  const float* lng = (const float*)d_in[11];
  const float* lnb = (const float*)d_in[12];

  char* ws = (char*)d_ws;
  size_t off = 0;
  auto alloc = [&](size_t bytes) { size_t o = off; off += (bytes + 255) & ~(size_t)255; return o; };
  const size_t WB = 768 * 768 * 2;           // bf16 weight bytes
  const size_t GB = (size_t)56 * ISTR * 2;   // gathered bf16 bytes
  u16* wqb = (u16*)(ws + alloc(WB));
  u16* wkb = (u16*)(ws + alloc(WB));
  u16* wvb = (u16*)(ws + alloc(WB));
  u16* wob = (u16*)(ws + alloc(WB));
  u16* Qg  = (u16*)(ws + alloc(GB));
  u16* Kg  = (u16*)(ws + alloc(GB));
  u16* VgT = (u16*)(ws + alloc(GB));
  uint32* Op32 = (uint32*)(ws + alloc((size_t)2 * 56 * 2048 * 32 * 4));
  float* Lsb  = (float*)(ws + alloc((size_t)2 * 56 * 2048 * 4));
  u16* xln = (u16*)(ws + alloc((size_t)16384 * 768 * 2));

  const int n4 = 768 * 768 / 4;
  cvt_w4<<<dim3(576, 4), 256, 0, stream>>>(Wq, Wk, Wv, Wo, wqb, wkb, wvb, wob, n4);

  qkv_fused<<<dim3(2304), 256, 0, stream>>>(
      query, key_, value, wqb, wkb, wvb, bq, bk, bv, Qg, Kg, VgT);

  dil_attn<<<dim3(1792), 256, 0, stream>>>(Qg, Kg, VgT, Op32, Lsb);
  ln_gather<<<dim3(16384), 256, 0, stream>>>(Op32, Lsb, lng, lnb, xln);
  out_gemm<<<dim3(768), 256, 0, stream>>>(xln, wob, bo, (float*)d_out);
}

// Round 9
// 317.710 us; speedup vs baseline: 1.0027x; 1.0027x over previous
//
#include <hip/hip_runtime.h>
#include <hip/hip_bf16.h>
#include <stdint.h>

typedef unsigned int uint32;
typedef unsigned short u16;
typedef __attribute__((ext_vector_type(4))) float f32x4;
typedef __attribute__((ext_vector_type(16))) float f32x16;
typedef __attribute__((ext_vector_type(8))) __bf16 bf16x8;
typedef __attribute__((ext_vector_type(8))) short i16x8;
typedef __attribute__((ext_vector_type(4))) short i16x4;
typedef __attribute__((ext_vector_type(4))) uint32 u32x4;

#define DEVINL static __device__ __forceinline__

DEVINL u16 f2bf(float f){
  uint32 u = __builtin_bit_cast(uint32, f);
  return (u16)((u + 0x7fffu + ((u >> 16) & 1u)) >> 16);  // RNE
}

DEVINL uint32 cvtpk(float lo, float hi){
  uint32 r;
  asm("v_cvt_pk_bf16_f32 %0, %1, %2" : "=v"(r) : "v"(lo), "v"(hi));
  return r;
}

// vdst.hi32lanes <-> vsrc.lo32lanes
DEVINL void permswap(uint32 &a, uint32 &b){
  asm volatile("s_nop 1\n\tv_permlane32_swap_b32 %0, %1" : "+v"(a), "+v"(b));
}

DEVINL f32x4 mfma16(bf16x8 a, bf16x8 b, f32x4 c){
  return __builtin_amdgcn_mfma_f32_16x16x32_bf16(a, b, c, 0, 0, 0);
}
DEVINL f32x16 mfma32(bf16x8 a, bf16x8 b, f32x16 c){
  return __builtin_amdgcn_mfma_f32_32x32x16_bf16(a, b, c, 0, 0, 0);
}
DEVINL f32x16 zero16(){
  f32x16 z;
  #pragma unroll
  for (int r = 0; r < 16; ++r) z[r] = 0.f;
  return z;
}

// async global->LDS, 16B per lane; LDS dest is wave-uniform base + lane*16
DEVINL void gload16(const u16* g, u16* l){
  __builtin_amdgcn_global_load_lds(
      (const __attribute__((address_space(1))) uint32*)g,
      (__attribute__((address_space(3))) uint32*)l, 16, 0, 0);
}
DEVINL void gload16f(const float* g, float* l){
  __builtin_amdgcn_global_load_lds(
      (const __attribute__((address_space(1))) uint32*)g,
      (__attribute__((address_space(3))) uint32*)l, 16, 0, 0);
}

static constexpr size_t ISTR = 2048 * 64;   // elems per attention instance
static constexpr float QSCALE = 0.18033688011112042f;  // log2(e)/8 folded into Q

// ---------------- weight f32 -> bf16 (all four in one dispatch) ----------------
__global__ void cvt_w4(const float* __restrict__ s0, const float* __restrict__ s1,
                       const float* __restrict__ s2, const float* __restrict__ s3,
                       u16* __restrict__ d0, u16* __restrict__ d1,
                       u16* __restrict__ d2, u16* __restrict__ d3, int n4){
  const int wsel = blockIdx.y;
  const float* src = wsel == 0 ? s0 : wsel == 1 ? s1 : wsel == 2 ? s2 : s3;
  u16* dst = wsel == 0 ? d0 : wsel == 1 ? d1 : wsel == 2 ? d2 : d3;
  int i = blockIdx.x * 256 + threadIdx.x;
  if (i < n4){
    f32x4 v = *(const f32x4*)(src + (size_t)i * 4);
    u16 o[4];
    #pragma unroll
    for (int j = 0; j < 4; ++j) o[j] = f2bf(v[j]);
    *(i16x4*)(dst + (size_t)i * 4) = *(const i16x4*)o;
  }
}

// ---------------- fused QKV projection GEMM ----------------
// grid (128, 18): y/6 = section (0:Q,1:K,2:V), (y%6)*128 = col tile.
// A (f32) and B (bf16) BOTH via global_load_lds; 3-buffer depth-2 counted-vmcnt pipeline.
__global__ __launch_bounds__(256) void qkv_fused(
    const float* __restrict__ X0, const float* __restrict__ X1, const float* __restrict__ X2,
    const u16* __restrict__ W0, const u16* __restrict__ W1, const u16* __restrict__ W2,
    const float* __restrict__ b0, const float* __restrict__ b1, const float* __restrict__ b2,
    u16* __restrict__ Y0, u16* __restrict__ Y1, u16* __restrict__ Y2)
{
  __shared__ float Af[3][128 * 32];   // 16KB each
  __shared__ u16  Bs[3][128 * 32];    // 8KB each
  const int tid = threadIdx.x;
  const int l = tid & 63, w = tid >> 6;
  const int l15 = l & 15, lh = l >> 4;
  const int wr = w >> 1, wc = w & 1;
  const int yb = blockIdx.y;
  const int sect = yb / 6;
  const int row0 = blockIdx.x * 128, col0 = (yb % 6) * 128;

  const float* X   = sect == 0 ? X0 : sect == 1 ? X1 : X2;
  const u16*   W   = sect == 0 ? W0 : sect == 1 ? W1 : W2;
  const float* bia_p = sect == 0 ? b0 : sect == 1 ? b1 : b2;
  u16*         Yg  = sect == 0 ? Y0 : sect == 1 ? Y1 : Y2;
  const float scale = sect == 0 ? QSCALE : 1.0f;
  const int tmode = (sect == 2) ? 1 : 0;

  // B staging: lane row gr=l>>2, src chunk pre-XORed (involution with read-side bxor)
  const int gr = l >> 2;
  const int gcx = ((l & 3) ^ ((gr >> 1) & 3)) * 8;
  const u16* wsrc0 = W + (size_t)(col0 + w * 32 + gr) * 768 + gcx;

  // A staging (f32): lane row ar=l>>3 (8 rows/gload), src f32-chunk pre-XORed by row&7
  const int ar = l >> 3;
  const int acx = ((l & 7) ^ (ar & 7)) * 4;
  const float* asrc0 = X + (size_t)(row0 + w * 32 + ar) * 768 + acx;

  f32x4 acc[4][4];
  #pragma unroll
  for (int i = 0; i < 4; ++i)
    #pragma unroll
    for (int j = 0; j < 4; ++j) acc[i][j] = f32x4{0.f, 0.f, 0.f, 0.f};

  auto STAGE = [&](int buf, int ks){   // 6 gloads per wave
    const u16* wsp = wsrc0 + ks * 32;
    gload16(wsp,            &Bs[buf][(w * 32) * 32]);
    gload16(wsp + 16 * 768, &Bs[buf][(w * 32 + 16) * 32]);
    const float* asp = asrc0 + ks * 32;
    gload16f(asp,            &Af[buf][(w * 32) * 32]);
    gload16f(asp +  8 * 768, &Af[buf][(w * 32 +  8) * 32]);
    gload16f(asp + 16 * 768, &Af[buf][(w * 32 + 16) * 32]);
    gload16f(asp + 24 * 768, &Af[buf][(w * 32 + 24) * 32]);
  };

  const int bxor = ((l15 >> 1) & 3) * 8;   // B read-side XOR (elems)
  const int rx = l15 & 7;                  // A read-side row XOR (16B chunks)

  auto COMPUTE = [&](int buf){
    bf16x8 af[4], bfr[4];
    #pragma unroll
    for (int mi = 0; mi < 4; ++mi) {
      const int r = wr * 64 + mi * 16 + l15;
      const int c0 = (lh * 2) ^ rx, c1 = (lh * 2 + 1) ^ rx;
      f32x4 p0 = *(const f32x4*)&Af[buf][r * 32 + c0 * 4];
      f32x4 p1 = *(const f32x4*)&Af[buf][r * 32 + c1 * 4];
      u32x4 pk = { cvtpk(p0[0], p0[1]), cvtpk(p0[2], p0[3]),
                   cvtpk(p1[0], p1[1]), cvtpk(p1[2], p1[3]) };
      af[mi] = __builtin_bit_cast(bf16x8, pk);
    }
    #pragma unroll
    for (int ni = 0; ni < 4; ++ni)
      bfr[ni] = *(const bf16x8*)&Bs[buf][(wc * 64 + ni * 16 + l15) * 32 + ((lh * 8) ^ bxor)];
    #pragma unroll
    for (int mi = 0; mi < 4; ++mi)
      #pragma unroll
      for (int ni = 0; ni < 4; ++ni)
        acc[mi][ni] = mfma16(af[mi], bfr[ni], acc[mi][ni]);
  };

  STAGE(0, 0);
  STAGE(1, 1);
  int cur = 0, stg = 2;
  for (int ks = 0; ks < 23; ++ks) {
    asm volatile("s_waitcnt vmcnt(6)" ::: "memory");  // step-ks loads done; ks+1 in flight
    __syncthreads();
    if (ks < 22) STAGE(stg, ks + 2);
    COMPUTE(cur);
    cur = (cur == 2) ? 0 : cur + 1;
    stg = (stg == 2) ? 0 : stg + 1;
  }
  asm volatile("s_waitcnt vmcnt(0)" ::: "memory");
  __syncthreads();
  COMPUTE(cur);   // step 23

  // scatter epilogue: C layout col=lane&15, row=(lane>>4)*4+reg  [m89]
  #pragma unroll
  for (int ni = 0; ni < 4; ++ni) {
    const int e = col0 + wc * 64 + ni * 16 + l15;
    const int h = e >> 6, d = e & 63;
    const int grp = h >> 2, hg = h & 3;
    const int instB = (grp == 0) ? 0 : (grp == 1) ? 32 : 48;
    const float bia = bia_p[e];
    #pragma unroll
    for (int mi = 0; mi < 4; ++mi) {
      #pragma unroll
      for (int r = 0; r < 4; ++r) {
        const int row = row0 + wr * 64 + mi * 16 + lh * 4 + r;
        const int b = row >> 13, nn = row & 8191;
        const int p = nn & ((2048 << grp) - 1);
        if ((p & ((1 << grp) - 1)) != grp) continue;   // off dilation grid
        const int seg = nn >> (11 + grp);
        const int t = (p - grp) >> grp;
        const int inst = instB + ((b * (4 >> grp) + seg) << 2) + hg;
        const u16 val = f2bf((acc[mi][ni][r] + bia) * scale);
        if (tmode == 0) Yg[(size_t)inst * ISTR + (size_t)t * 64 + d] = val;
        else            Yg[(size_t)inst * ISTR + (size_t)d * 2048 + t] = val;
      }
    }
  }
}

// ---------------- dilated flash attention: 4 waves, LDS-staged K/V, split-K 2 ----------------
__global__ __launch_bounds__(256) void dil_attn(
    const u16* __restrict__ Qg, const u16* __restrict__ Kg,
    const u16* __restrict__ VgT, uint32* __restrict__ Op32, float* __restrict__ Ls)
{
  __shared__ u16 Kb[2][64 * 64];
  __shared__ u16 Vb[2][64 * 64];
  const int tid = threadIdx.x;
  const int w = tid >> 6, l = tid & 63;
  const int l31 = l & 31, hi = l >> 5;
  const int id = blockIdx.x;
  const int nid = (id & 7) * 224 + (id >> 3);
  const int inst = nid >> 5, rem = nid & 31;
  const int qb = rem >> 1, kh = rem & 1;
  const size_t ibase = (size_t)inst * ISTR;
  const int qbase = qb * 128 + w * 32;
  const int k0base = kh * 1024;

  const u16* qlane = Qg + ibase + (size_t)(qbase + l31) * 64 + hi * 8;
  const bf16x8 qf0 = *(const bf16x8*)(qlane);
  const bf16x8 qf1 = *(const bf16x8*)(qlane + 16);
  const bf16x8 qf2 = *(const bf16x8*)(qlane + 32);
  const bf16x8 qf3 = *(const bf16x8*)(qlane + 48);

  const int srow = l >> 3;
  const int scol = ((l & 7) ^ (srow & 7)) << 3;
  const u16* kgs = Kg  + ibase + (size_t)srow * 64 + scol;
  const u16* vgs = VgT + ibase + (size_t)srow * 2048 + scol;

  f32x16 acc0 = zero16(), acc1 = zero16(), rs = zero16();
  const int sxor = (l31 & 7) << 3;
  const bf16x8 ones = __builtin_bit_cast(bf16x8,
      u32x4{0x3F803F80u, 0x3F803F80u, 0x3F803F80u, 0x3F803F80u});

  auto STAGE = [&](int buf, int k0){
    #pragma unroll
    for (int q = 0; q < 2; ++q){
      const int rb = w * 16 + q * 8;
      gload16(kgs + (size_t)(k0 + rb) * 64, &Kb[buf][rb * 64]);
      gload16(vgs + (size_t)rb * 2048 + k0, &Vb[buf][rb * 64]);
    }
  };

  STAGE(0, k0base);
  asm volatile("s_waitcnt vmcnt(0)");
  __syncthreads();

  int cur = 0;
  for (int step = 0; step < 16; ++step) {
    if (step < 15) STAGE(cur ^ 1, k0base + ((step + 1) << 6));
    const u16* kt = &Kb[cur][0];
    const u16* vt = &Vb[cur][0];
    #pragma unroll
    for (int s = 0; s < 2; ++s) {
      const int ksub = s * 32;
      const int krow = (ksub + l31) * 64;
      bf16x8 kc0 = *(const bf16x8*)&kt[krow + ((hi * 8)      ^ sxor)];
      bf16x8 kc1 = *(const bf16x8*)&kt[krow + ((16 + hi * 8) ^ sxor)];
      bf16x8 kc2 = *(const bf16x8*)&kt[krow + ((32 + hi * 8) ^ sxor)];
      bf16x8 kc3 = *(const bf16x8*)&kt[krow + ((48 + hi * 8) ^ sxor)];

      f32x16 sT = zero16();
      sT = mfma32(kc0, qf0, sT);
      sT = mfma32(kc1, qf1, sT);
      sT = mfma32(kc2, qf2, sT);
      sT = mfma32(kc3, qf3, sT);

      #pragma unroll
      for (int r = 0; r < 16; ++r) sT[r] = __builtin_amdgcn_exp2f(sT[r]);

      uint32 cw0 = cvtpk(sT[0],  sT[1]),  cw1 = cvtpk(sT[2],  sT[3]);
      uint32 cw2 = cvtpk(sT[4],  sT[5]),  cw3 = cvtpk(sT[6],  sT[7]);
      uint32 cw4 = cvtpk(sT[8],  sT[9]),  cw5 = cvtpk(sT[10], sT[11]);
      uint32 cw6 = cvtpk(sT[12], sT[13]), cw7 = cvtpk(sT[14], sT[15]);
      permswap(cw0, cw2); permswap(cw1, cw3);
      permswap(cw4, cw6); permswap(cw5, cw7);
      bf16x8 pa0 = __builtin_bit_cast(bf16x8, u32x4{cw0, cw1, cw2, cw3});
      bf16x8 pa1 = __builtin_bit_cast(bf16x8, u32x4{cw4, cw5, cw6, cw7});

      const int vr0 = l31 * 64, vr1 = (l31 + 32) * 64;
      bf16x8 v00 = *(const bf16x8*)&vt[vr0 + ((ksub + hi * 8)      ^ sxor)];
      bf16x8 v01 = *(const bf16x8*)&vt[vr0 + ((ksub + 16 + hi * 8) ^ sxor)];
      bf16x8 v10 = *(const bf16x8*)&vt[vr1 + ((ksub + hi * 8)      ^ sxor)];
      bf16x8 v11 = *(const bf16x8*)&vt[vr1 + ((ksub + 16 + hi * 8) ^ sxor)];

      rs   = mfma32(pa0, ones, rs);
      rs   = mfma32(pa1, ones, rs);
      acc0 = mfma32(pa0, v00, acc0);
      acc0 = mfma32(pa1, v01, acc0);
      acc1 = mfma32(pa0, v10, acc1);
      acc1 = mfma32(pa1, v11, acc1);
    }
    asm volatile("s_waitcnt vmcnt(0)");
    __syncthreads();
    cur ^= 1;
  }

  if (l31 == 0) {
    float* lsp = Ls + ((size_t)kh * 56 + inst) * 2048 + qbase;
    #pragma unroll
    for (int r = 0; r < 16; ++r) {
      const int qrow = (r & 3) + 8 * (r >> 2) + 4 * hi;
      lsp[qrow] = rs[r];
    }
  }
  uint32* op = Op32 + (size_t)kh * (56u * 2048u * 32u)
                    + ((size_t)inst * 2048 + qbase) * 32 + l31;
  #pragma unroll
  for (int r = 0; r < 16; ++r) {
    const int qrow = (r & 3) + 8 * (r >> 2) + 4 * hi;
    op[(size_t)qrow * 32] = cvtpk(acc0[r], acc1[r]);
  }
}

// ---------------- gather + combine split-K + normalize + LayerNorm -> xln ----------------
__global__ __launch_bounds__(256) void ln_gather(
    const uint32* __restrict__ Op32, const float* __restrict__ Ls,
    const float* __restrict__ gamma, const float* __restrict__ beta,
    u16* __restrict__ xln)
{
  const int row = blockIdx.x;            // 0..16383
  const int b = row >> 13, nn = row & 8191;
  const int tid = threadIdx.x;
  const size_t KHOFF = 56u * 2048u * 32u;
  float v[3];
  #pragma unroll
  for (int j = 0; j < 3; ++j) {
    const int e = tid + j * 256;
    const int h = e >> 6, d = e & 63;
    const int grp = h >> 2, hg = h & 3;
    const int p = nn & ((2048 << grp) - 1);
    float val = 0.f;
    if ((p & ((1 << grp) - 1)) == grp) {
      const int seg = nn >> (11 + grp);
      const int instB = (grp == 0) ? 0 : (grp == 1) ? 32 : 48;
      const int inst = instB + ((b * (4 >> grp) + seg) << 2) + hg;
      const int t = (p - grp) >> grp;
      const size_t wbase = ((size_t)inst * 2048 + t) * 32 + (d & 31);
      const uint32 w0 = Op32[wbase];
      const uint32 w1 = Op32[wbase + KHOFF];
      const float o0 = __builtin_bit_cast(float, d < 32 ? (w0 << 16) : (w0 & 0xFFFF0000u));
      const float o1 = __builtin_bit_cast(float, d < 32 ? (w1 << 16) : (w1 & 0xFFFF0000u));
      const float s = Ls[(size_t)inst * 2048 + t] + Ls[(size_t)(56 * 2048) + inst * 2048 + t];
      val = (o0 + o1) * (1.0f / (3.0f * s));
    }
    v[j] = val;
  }
  float s = v[0] + v[1] + v[2];
  float q = v[0]*v[0] + v[1]*v[1] + v[2]*v[2];
  #pragma unroll
  for (int off = 1; off < 64; off <<= 1) { s += __shfl_xor(s, off); q += __shfl_xor(q, off); }
  __shared__ float red[8];
  const int w = tid >> 6, l = tid & 63;
  if (l == 0) { red[w] = s; red[4 + w] = q; }
  __syncthreads();
  s = red[0] + red[1] + red[2] + red[3];
  q = red[4] + red[5] + red[6] + red[7];
  const float mu = s * (1.f / 768.f);
  const float var = q * (1.f / 768.f) - mu * mu;
  const float rs = rsqrtf(var + 1e-5f);
  #pragma unroll
  for (int j = 0; j < 3; ++j) {
    const int e = tid + j * 256;
    xln[(size_t)row * 768 + e] = f2bf((v[j] - mu) * rs * gamma[e] + beta[e]);
  }
}

// ---------------- output projection GEMM (3-buffer counted-vmcnt, all bf16) ----------------
__global__ __launch_bounds__(256) void out_gemm(
    const u16* __restrict__ Xb, const u16* __restrict__ W,
    const float* __restrict__ bias, float* __restrict__ out)
{
  __shared__ u16 As[3][128 * 32];
  __shared__ u16 Bs[3][128 * 32];
  const int tid = threadIdx.x;
  const int l = tid & 63, w = tid >> 6;
  const int l15 = l & 15, lh = l >> 4;
  const int wr = w >> 1, wc = w & 1;
  const int row0 = blockIdx.x * 128, col0 = blockIdx.y * 128;

  const int gr = l >> 2;
  const int gcx = ((l & 3) ^ ((gr >> 1) & 3)) * 8;   // pre-swizzled source chunk [T2]
  const u16* asrc0 = Xb + (size_t)(row0 + w * 32 + gr) * 768 + gcx;
  const u16* wsrc0 = W  + (size_t)(col0 + w * 32 + gr) * 768 + gcx;

  f32x4 acc[4][4];
  #pragma unroll
  for (int i = 0; i < 4; ++i)
    #pragma unroll
    for (int j = 0; j < 4; ++j) acc[i][j] = f32x4{0.f, 0.f, 0.f, 0.f};

  auto STAGE = [&](int buf, int ks){   // 4 gloads per wave
    const u16* as = asrc0 + ks * 32;
    const u16* ws = wsrc0 + ks * 32;
    gload16(as,            &As[buf][(w * 32) * 32]);
    gload16(as + 16 * 768, &As[buf][(w * 32 + 16) * 32]);
    gload16(ws,            &Bs[buf][(w * 32) * 32]);
    gload16(ws + 16 * 768, &Bs[buf][(w * 32 + 16) * 32]);
  };

  const int bxor = ((l15 >> 1) & 3) * 8;
  auto COMPUTE = [&](int buf){
    bf16x8 af[4], bfr[4];
    #pragma unroll
    for (int mi = 0; mi < 4; ++mi)
      af[mi] = *(const bf16x8*)&As[buf][(wr * 64 + mi * 16 + l15) * 32 + ((lh * 8) ^ bxor)];
    #pragma unroll
    for (int ni = 0; ni < 4; ++ni)
      bfr[ni] = *(const bf16x8*)&Bs[buf][(wc * 64 + ni * 16 + l15) * 32 + ((lh * 8) ^ bxor)];
    #pragma unroll
    for (int mi = 0; mi < 4; ++mi)
      #pragma unroll
      for (int ni = 0; ni < 4; ++ni)
        acc[mi][ni] = mfma16(af[mi], bfr[ni], acc[mi][ni]);
  };

  STAGE(0, 0);
  STAGE(1, 1);
  int cur = 0, stg = 2;
  for (int ks = 0; ks < 23; ++ks) {
    asm volatile("s_waitcnt vmcnt(4)" ::: "memory");
    __syncthreads();
    if (ks < 22) STAGE(stg, ks + 2);
    COMPUTE(cur);
    cur = (cur == 2) ? 0 : cur + 1;
    stg = (stg == 2) ? 0 : stg + 1;
  }
  asm volatile("s_waitcnt vmcnt(0)" ::: "memory");
  __syncthreads();
  COMPUTE(cur);

  #pragma unroll
  for (int ni = 0; ni < 4; ++ni) {
    const int e = col0 + wc * 64 + ni * 16 + l15;
    const float bia = bias[e];
    #pragma unroll
    for (int mi = 0; mi < 4; ++mi) {
      #pragma unroll
      for (int r = 0; r < 4; ++r) {
        const int row = row0 + wr * 64 + mi * 16 + lh * 4 + r;
        out[(size_t)row * 768 + e] = acc[mi][ni][r] + bia;
      }
    }
  }
}

extern "C" void kernel_launch(void* const* d_in, const int* in_sizes, int n_in,
                              void* d_out, int out_size, void* d_ws, size_t ws_size,
                              hipStream_t stream) {
  const float* query = (const float*)d_in[0];
  const float* key_  = (const float*)d_in[1];
  const float* value = (const float*)d_in[2];
  const float* Wq = (const float*)d_in[3];
  const float* bq = (const float*)d_in[4];
  const float* Wk = (const float*)d_in[5];
  const float* bk = (const float*)d_in[6];
  const float* Wv = (const float*)d_in[7];
  const float* bv = (const float*)d_in[8];
  const float* Wo = (const float*)d_in[9];
  const float* bo = (const float*)d_in[10];
  const float* lng = (const float*)d_in[11];
  const float* lnb = (const float*)d_in[12];

  char* ws = (char*)d_ws;
  size_t off = 0;
  auto alloc = [&](size_t bytes) { size_t o = off; off += (bytes + 255) & ~(size_t)255; return o; };
  const size_t WB = 768 * 768 * 2;           // bf16 weight bytes
  const size_t GB = (size_t)56 * ISTR * 2;   // gathered bf16 bytes
  u16* wqb = (u16*)(ws + alloc(WB));
  u16* wkb = (u16*)(ws + alloc(WB));
  u16* wvb = (u16*)(ws + alloc(WB));
  u16* wob = (u16*)(ws + alloc(WB));
  u16* Qg  = (u16*)(ws + alloc(GB));
  u16* Kg  = (u16*)(ws + alloc(GB));
  u16* VgT = (u16*)(ws + alloc(GB));
  uint32* Op32 = (uint32*)(ws + alloc((size_t)2 * 56 * 2048 * 32 * 4));
  float* Lsb  = (float*)(ws + alloc((size_t)2 * 56 * 2048 * 4));
  u16* xln = (u16*)(ws + alloc((size_t)16384 * 768 * 2));

  const int n4 = 768 * 768 / 4;
  cvt_w4<<<dim3(576, 4), 256, 0, stream>>>(Wq, Wk, Wv, Wo, wqb, wkb, wvb, wob, n4);

  qkv_fused<<<dim3(128, 18), 256, 0, stream>>>(
      query, key_, value, wqb, wkb, wvb, bq, bk, bv, Qg, Kg, VgT);

  dil_attn<<<dim3(1792), 256, 0, stream>>>(Qg, Kg, VgT, Op32, Lsb);
  ln_gather<<<dim3(16384), 256, 0, stream>>>(Op32, Lsb, lng, lnb, xln);
  out_gemm<<<dim3(128, 6), 256, 0, stream>>>(xln, wob, bo, (float*)d_out);
}

// Round 10
// 278.947 us; speedup vs baseline: 1.1420x; 1.1390x over previous
//
#include <hip/hip_runtime.h>
#include <hip/hip_bf16.h>
#include <stdint.h>

typedef unsigned int uint32;
typedef unsigned short u16;
typedef __attribute__((ext_vector_type(4))) float f32x4;
typedef __attribute__((ext_vector_type(16))) float f32x16;
typedef __attribute__((ext_vector_type(8))) __bf16 bf16x8;
typedef __attribute__((ext_vector_type(8))) short i16x8;
typedef __attribute__((ext_vector_type(4))) short i16x4;
typedef __attribute__((ext_vector_type(2))) uint32 u32x2;
typedef __attribute__((ext_vector_type(4))) uint32 u32x4;

#define DEVINL static __device__ __forceinline__

DEVINL u16 f2bf(float f){
  uint32 u = __builtin_bit_cast(uint32, f);
  return (u16)((u + 0x7fffu + ((u >> 16) & 1u)) >> 16);  // RNE
}

DEVINL uint32 cvtpk(float lo, float hi){
  uint32 r;
  asm("v_cvt_pk_bf16_f32 %0, %1, %2" : "=v"(r) : "v"(lo), "v"(hi));
  return r;
}

// vdst.hi32lanes <-> vsrc.lo32lanes
DEVINL void permswap(uint32 &a, uint32 &b){
  asm volatile("s_nop 1\n\tv_permlane32_swap_b32 %0, %1" : "+v"(a), "+v"(b));
}

DEVINL f32x4 mfma16(bf16x8 a, bf16x8 b, f32x4 c){
  return __builtin_amdgcn_mfma_f32_16x16x32_bf16(a, b, c, 0, 0, 0);
}
DEVINL f32x16 mfma32(bf16x8 a, bf16x8 b, f32x16 c){
  return __builtin_amdgcn_mfma_f32_32x32x16_bf16(a, b, c, 0, 0, 0);
}
DEVINL f32x16 zero16(){
  f32x16 z;
  #pragma unroll
  for (int r = 0; r < 16; ++r) z[r] = 0.f;
  return z;
}

// async global->LDS, 16B per lane; LDS dest is wave-uniform base + lane*16
DEVINL void gload16(const u16* g, u16* l){
  __builtin_amdgcn_global_load_lds(
      (const __attribute__((address_space(1))) uint32*)g,
      (__attribute__((address_space(3))) uint32*)l, 16, 0, 0);
}

static constexpr size_t ISTR = 2048 * 64;   // elems per attention instance
static constexpr float QSCALE = 0.18033688011112042f;  // log2(e)/8 folded into Q

// ---------------- weight f32 -> bf16 (all four in one dispatch) ----------------
__global__ void cvt_w4(const float* __restrict__ s0, const float* __restrict__ s1,
                       const float* __restrict__ s2, const float* __restrict__ s3,
                       u16* __restrict__ d0, u16* __restrict__ d1,
                       u16* __restrict__ d2, u16* __restrict__ d3, int n4){
  const int wsel = blockIdx.y;
  const float* src = wsel == 0 ? s0 : wsel == 1 ? s1 : wsel == 2 ? s2 : s3;
  u16* dst = wsel == 0 ? d0 : wsel == 1 ? d1 : wsel == 2 ? d2 : d3;
  int i = blockIdx.x * 256 + threadIdx.x;
  if (i < n4){
    f32x4 v = *(const f32x4*)(src + (size_t)i * 4);
    u32x2 o = { cvtpk(v[0], v[1]), cvtpk(v[2], v[3]) };
    *(u32x2*)(dst + (size_t)i * 4) = o;
  }
}

// ---------------- X f32 -> bf16 (Q,K,V inputs; one dispatch) ----------------
__global__ void cvt_x(const float* __restrict__ s0, const float* __restrict__ s1,
                      const float* __restrict__ s2,
                      u16* __restrict__ d0, u16* __restrict__ d1, u16* __restrict__ d2){
  const int t = blockIdx.y;
  const float* src = t == 0 ? s0 : t == 1 ? s1 : s2;
  u16* dst = t == 0 ? d0 : t == 1 ? d1 : d2;
  const int n4 = 16384 * 768 / 4;
  for (int i = blockIdx.x * 256 + threadIdx.x; i < n4; i += gridDim.x * 256){
    f32x4 v = *(const f32x4*)(src + (size_t)i * 4);
    u32x2 o = { cvtpk(v[0], v[1]), cvtpk(v[2], v[3]) };
    *(u32x2*)(dst + (size_t)i * 4) = o;
  }
}

// ---------------- fused QKV projection GEMM (all-bf16, out_gemm structure) ----------------
// grid (128, 18): y/6 = section (0:Q,1:K,2:V), (y%6)*128 = col tile.
// A (bf16 pre-converted X) and B (bf16 weight) via swizzled global_load_lds, 2-buffer.
__global__ __launch_bounds__(256) void qkv_fused(
    const u16* __restrict__ X0, const u16* __restrict__ X1, const u16* __restrict__ X2,
    const u16* __restrict__ W0, const u16* __restrict__ W1, const u16* __restrict__ W2,
    const float* __restrict__ b0, const float* __restrict__ b1, const float* __restrict__ b2,
    u16* __restrict__ Y0, u16* __restrict__ Y1, u16* __restrict__ Y2)
{
  __shared__ u16 As[2][128 * 32];
  __shared__ u16 Bs[2][128 * 32];
  const int tid = threadIdx.x;
  const int l = tid & 63, w = tid >> 6;
  const int l15 = l & 15, lh = l >> 4;
  const int wr = w >> 1, wc = w & 1;
  const int yb = blockIdx.y;
  const int sect = yb / 6;
  const int row0 = blockIdx.x * 128, col0 = (yb % 6) * 128;

  const u16* X = sect == 0 ? X0 : sect == 1 ? X1 : X2;
  const u16* W = sect == 0 ? W0 : sect == 1 ? W1 : W2;
  const float* bia_p = sect == 0 ? b0 : sect == 1 ? b1 : b2;
  u16* Yg = sect == 0 ? Y0 : sect == 1 ? Y1 : Y2;
  const float scale = sect == 0 ? QSCALE : 1.0f;
  const int tmode = (sect == 2) ? 1 : 0;

  const int gr = l >> 2;
  const int gcx = ((l & 3) ^ ((gr >> 1) & 3)) * 8;   // pre-swizzled source chunk [T2]
  const u16* asrc0 = X + (size_t)(row0 + w * 32 + gr) * 768 + gcx;
  const u16* wsrc0 = W + (size_t)(col0 + w * 32 + gr) * 768 + gcx;

  f32x4 acc[4][4];
  #pragma unroll
  for (int i = 0; i < 4; ++i)
    #pragma unroll
    for (int j = 0; j < 4; ++j) acc[i][j] = f32x4{0.f, 0.f, 0.f, 0.f};

  auto STAGE = [&](int buf, int ks){
    const u16* as = asrc0 + ks * 32;
    const u16* ws = wsrc0 + ks * 32;
    gload16(as,            &As[buf][(w * 32) * 32]);
    gload16(as + 16 * 768, &As[buf][(w * 32 + 16) * 32]);
    gload16(ws,            &Bs[buf][(w * 32) * 32]);
    gload16(ws + 16 * 768, &Bs[buf][(w * 32 + 16) * 32]);
  };

  STAGE(0, 0);
  asm volatile("s_waitcnt vmcnt(0)");
  __syncthreads();

  const int bxor = ((l15 >> 1) & 3) * 8;   // read-side XOR
  int cur = 0;
  for (int ks = 0; ks < 24; ++ks) {
    const int nxt = cur ^ 1;
    if (ks < 23) STAGE(nxt, ks + 1);
    bf16x8 af[4], bfr[4];
    #pragma unroll
    for (int mi = 0; mi < 4; ++mi)
      af[mi] = *(const bf16x8*)&As[cur][(wr * 64 + mi * 16 + l15) * 32 + ((lh * 8) ^ bxor)];
    #pragma unroll
    for (int ni = 0; ni < 4; ++ni)
      bfr[ni] = *(const bf16x8*)&Bs[cur][(wc * 64 + ni * 16 + l15) * 32 + ((lh * 8) ^ bxor)];
    #pragma unroll
    for (int mi = 0; mi < 4; ++mi)
      #pragma unroll
      for (int ni = 0; ni < 4; ++ni)
        acc[mi][ni] = mfma16(af[mi], bfr[ni], acc[mi][ni]);
    asm volatile("s_waitcnt vmcnt(0)");
    __syncthreads();
    cur = nxt;
  }

  // scatter epilogue: C layout col=lane&15, row=(lane>>4)*4+reg  [m89]
  #pragma unroll
  for (int ni = 0; ni < 4; ++ni) {
    const int e = col0 + wc * 64 + ni * 16 + l15;
    const int h = e >> 6, d = e & 63;
    const int grp = h >> 2, hg = h & 3;
    const int instB = (grp == 0) ? 0 : (grp == 1) ? 32 : 48;
    const float bia = bia_p[e];
    #pragma unroll
    for (int mi = 0; mi < 4; ++mi) {
      #pragma unroll
      for (int r = 0; r < 4; ++r) {
        const int row = row0 + wr * 64 + mi * 16 + lh * 4 + r;
        const int b = row >> 13, nn = row & 8191;
        const int p = nn & ((2048 << grp) - 1);
        if ((p & ((1 << grp) - 1)) != grp) continue;   // off dilation grid
        const int seg = nn >> (11 + grp);
        const int t = (p - grp) >> grp;
        const int inst = instB + ((b * (4 >> grp) + seg) << 2) + hg;
        const u16 val = f2bf((acc[mi][ni][r] + bia) * scale);
        if (tmode == 0) Yg[(size_t)inst * ISTR + (size_t)t * 64 + d] = val;
        else            Yg[(size_t)inst * ISTR + (size_t)d * 2048 + t] = val;
      }
    }
  }
}

// ---------------- dilated flash attention: 4 waves, LDS-staged K/V, split-K 2 ----------------
__global__ __launch_bounds__(256) void dil_attn(
    const u16* __restrict__ Qg, const u16* __restrict__ Kg,
    const u16* __restrict__ VgT, uint32* __restrict__ Op32, float* __restrict__ Ls)
{
  __shared__ u16 Kb[2][64 * 64];
  __shared__ u16 Vb[2][64 * 64];
  const int tid = threadIdx.x;
  const int w = tid >> 6, l = tid & 63;
  const int l31 = l & 31, hi = l >> 5;
  const int id = blockIdx.x;
  const int nid = (id & 7) * 224 + (id >> 3);
  const int inst = nid >> 5, rem = nid & 31;
  const int qb = rem >> 1, kh = rem & 1;
  const size_t ibase = (size_t)inst * ISTR;
  const int qbase = qb * 128 + w * 32;
  const int k0base = kh * 1024;

  const u16* qlane = Qg + ibase + (size_t)(qbase + l31) * 64 + hi * 8;
  const bf16x8 qf0 = *(const bf16x8*)(qlane);
  const bf16x8 qf1 = *(const bf16x8*)(qlane + 16);
  const bf16x8 qf2 = *(const bf16x8*)(qlane + 32);
  const bf16x8 qf3 = *(const bf16x8*)(qlane + 48);

  const int srow = l >> 3;
  const int scol = ((l & 7) ^ (srow & 7)) << 3;
  const u16* kgs = Kg  + ibase + (size_t)srow * 64 + scol;
  const u16* vgs = VgT + ibase + (size_t)srow * 2048 + scol;

  f32x16 acc0 = zero16(), acc1 = zero16(), rs = zero16();
  const int sxor = (l31 & 7) << 3;
  const bf16x8 ones = __builtin_bit_cast(bf16x8,
      u32x4{0x3F803F80u, 0x3F803F80u, 0x3F803F80u, 0x3F803F80u});

  auto STAGE = [&](int buf, int k0){
    #pragma unroll
    for (int q = 0; q < 2; ++q){
      const int rb = w * 16 + q * 8;
      gload16(kgs + (size_t)(k0 + rb) * 64, &Kb[buf][rb * 64]);
      gload16(vgs + (size_t)rb * 2048 + k0, &Vb[buf][rb * 64]);
    }
  };

  STAGE(0, k0base);
  asm volatile("s_waitcnt vmcnt(0)");
  __syncthreads();

  int cur = 0;
  for (int step = 0; step < 16; ++step) {
    if (step < 15) STAGE(cur ^ 1, k0base + ((step + 1) << 6));
    const u16* kt = &Kb[cur][0];
    const u16* vt = &Vb[cur][0];
    #pragma unroll
    for (int s = 0; s < 2; ++s) {
      const int ksub = s * 32;
      const int krow = (ksub + l31) * 64;
      bf16x8 kc0 = *(const bf16x8*)&kt[krow + ((hi * 8)      ^ sxor)];
      bf16x8 kc1 = *(const bf16x8*)&kt[krow + ((16 + hi * 8) ^ sxor)];
      bf16x8 kc2 = *(const bf16x8*)&kt[krow + ((32 + hi * 8) ^ sxor)];
      bf16x8 kc3 = *(const bf16x8*)&kt[krow + ((48 + hi * 8) ^ sxor)];

      f32x16 sT = zero16();
      sT = mfma32(kc0, qf0, sT);
      sT = mfma32(kc1, qf1, sT);
      sT = mfma32(kc2, qf2, sT);
      sT = mfma32(kc3, qf3, sT);

      #pragma unroll
      for (int r = 0; r < 16; ++r) sT[r] = __builtin_amdgcn_exp2f(sT[r]);

      uint32 cw0 = cvtpk(sT[0],  sT[1]),  cw1 = cvtpk(sT[2],  sT[3]);
      uint32 cw2 = cvtpk(sT[4],  sT[5]),  cw3 = cvtpk(sT[6],  sT[7]);
      uint32 cw4 = cvtpk(sT[8],  sT[9]),  cw5 = cvtpk(sT[10], sT[11]);
      uint32 cw6 = cvtpk(sT[12], sT[13]), cw7 = cvtpk(sT[14], sT[15]);
      permswap(cw0, cw2); permswap(cw1, cw3);
      permswap(cw4, cw6); permswap(cw5, cw7);
      bf16x8 pa0 = __builtin_bit_cast(bf16x8, u32x4{cw0, cw1, cw2, cw3});
      bf16x8 pa1 = __builtin_bit_cast(bf16x8, u32x4{cw4, cw5, cw6, cw7});

      const int vr0 = l31 * 64, vr1 = (l31 + 32) * 64;
      bf16x8 v00 = *(const bf16x8*)&vt[vr0 + ((ksub + hi * 8)      ^ sxor)];
      bf16x8 v01 = *(const bf16x8*)&vt[vr0 + ((ksub + 16 + hi * 8) ^ sxor)];
      bf16x8 v10 = *(const bf16x8*)&vt[vr1 + ((ksub + hi * 8)      ^ sxor)];
      bf16x8 v11 = *(const bf16x8*)&vt[vr1 + ((ksub + 16 + hi * 8) ^ sxor)];

      rs   = mfma32(pa0, ones, rs);
      rs   = mfma32(pa1, ones, rs);
      acc0 = mfma32(pa0, v00, acc0);
      acc0 = mfma32(pa1, v01, acc0);
      acc1 = mfma32(pa0, v10, acc1);
      acc1 = mfma32(pa1, v11, acc1);
    }
    asm volatile("s_waitcnt vmcnt(0)");
    __syncthreads();
    cur ^= 1;
  }

  if (l31 == 0) {
    float* lsp = Ls + ((size_t)kh * 56 + inst) * 2048 + qbase;
    #pragma unroll
    for (int r = 0; r < 16; ++r) {
      const int qrow = (r & 3) + 8 * (r >> 2) + 4 * hi;
      lsp[qrow] = rs[r];
    }
  }
  uint32* op = Op32 + (size_t)kh * (56u * 2048u * 32u)
                    + ((size_t)inst * 2048 + qbase) * 32 + l31;
  #pragma unroll
  for (int r = 0; r < 16; ++r) {
    const int qrow = (r & 3) + 8 * (r >> 2) + 4 * hi;
    op[(size_t)qrow * 32] = cvtpk(acc0[r], acc1[r]);
  }
}

// ---------------- gather + combine split-K + normalize + LayerNorm -> xln ----------------
__global__ __launch_bounds__(256) void ln_gather(
    const uint32* __restrict__ Op32, const float* __restrict__ Ls,
    const float* __restrict__ gamma, const float* __restrict__ beta,
    u16* __restrict__ xln)
{
  const int row = blockIdx.x;            // 0..16383
  const int b = row >> 13, nn = row & 8191;
  const int tid = threadIdx.x;
  const size_t KHOFF = 56u * 2048u * 32u;
  float v[3];
  #pragma unroll
  for (int j = 0; j < 3; ++j) {
    const int e = tid + j * 256;
    const int h = e >> 6, d = e & 63;
    const int grp = h >> 2, hg = h & 3;
    const int p = nn & ((2048 << grp) - 1);
    float val = 0.f;
    if ((p & ((1 << grp) - 1)) == grp) {
      const int seg = nn >> (11 + grp);
      const int instB = (grp == 0) ? 0 : (grp == 1) ? 32 : 48;
      const int inst = instB + ((b * (4 >> grp) + seg) << 2) + hg;
      const int t = (p - grp) >> grp;
      const size_t wbase = ((size_t)inst * 2048 + t) * 32 + (d & 31);
      const uint32 w0 = Op32[wbase];
      const uint32 w1 = Op32[wbase + KHOFF];
      const float o0 = __builtin_bit_cast(float, d < 32 ? (w0 << 16) : (w0 & 0xFFFF0000u));
      const float o1 = __builtin_bit_cast(float, d < 32 ? (w1 << 16) : (w1 & 0xFFFF0000u));
      const float s = Ls[(size_t)inst * 2048 + t] + Ls[(size_t)(56 * 2048) + inst * 2048 + t];
      val = (o0 + o1) * (1.0f / (3.0f * s));
    }
    v[j] = val;
  }
  float s = v[0] + v[1] + v[2];
  float q = v[0]*v[0] + v[1]*v[1] + v[2]*v[2];
  #pragma unroll
  for (int off = 1; off < 64; off <<= 1) { s += __shfl_xor(s, off); q += __shfl_xor(q, off); }
  __shared__ float red[8];
  const int w = tid >> 6, l = tid & 63;
  if (l == 0) { red[w] = s; red[4 + w] = q; }
  __syncthreads();
  s = red[0] + red[1] + red[2] + red[3];
  q = red[4] + red[5] + red[6] + red[7];
  const float mu = s * (1.f / 768.f);
  const float var = q * (1.f / 768.f) - mu * mu;
  const float rs = rsqrtf(var + 1e-5f);
  #pragma unroll
  for (int j = 0; j < 3; ++j) {
    const int e = tid + j * 256;
    xln[(size_t)row * 768 + e] = f2bf((v[j] - mu) * rs * gamma[e] + beta[e]);
  }
}

// ---------------- output projection GEMM (bf16 A and B via swizzled global_load_lds) ----------------
__global__ __launch_bounds__(256) void out_gemm(
    const u16* __restrict__ Xb, const u16* __restrict__ W,
    const float* __restrict__ bias, float* __restrict__ out)
{
  __shared__ u16 As[2][128 * 32];
  __shared__ u16 Bs[2][128 * 32];
  const int tid = threadIdx.x;
  const int l = tid & 63, w = tid >> 6;
  const int l15 = l & 15, lh = l >> 4;
  const int wr = w >> 1, wc = w & 1;
  const int row0 = blockIdx.x * 128, col0 = blockIdx.y * 128;

  const int gr = l >> 2;
  const int gcx = ((l & 3) ^ ((gr >> 1) & 3)) * 8;   // pre-swizzled source chunk [T2]
  const u16* asrc0 = Xb + (size_t)(row0 + w * 32 + gr) * 768 + gcx;
  const u16* wsrc0 = W  + (size_t)(col0 + w * 32 + gr) * 768 + gcx;

  f32x4 acc[4][4];
  #pragma unroll
  for (int i = 0; i < 4; ++i)
    #pragma unroll
    for (int j = 0; j < 4; ++j) acc[i][j] = f32x4{0.f, 0.f, 0.f, 0.f};

  auto STAGE = [&](int buf, int ks){
    const u16* as = asrc0 + ks * 32;
    const u16* ws = wsrc0 + ks * 32;
    gload16(as,            &As[buf][(w * 32) * 32]);
    gload16(as + 16 * 768, &As[buf][(w * 32 + 16) * 32]);
    gload16(ws,            &Bs[buf][(w * 32) * 32]);
    gload16(ws + 16 * 768, &Bs[buf][(w * 32 + 16) * 32]);
  };

  STAGE(0, 0);
  asm volatile("s_waitcnt vmcnt(0)");
  __syncthreads();

  const int bxor = ((l15 >> 1) & 3) * 8;   // read-side XOR
  int cur = 0;
  for (int ks = 0; ks < 24; ++ks) {
    const int nxt = cur ^ 1;
    if (ks < 23) STAGE(nxt, ks + 1);
    bf16x8 af[4], bfr[4];
    #pragma unroll
    for (int mi = 0; mi < 4; ++mi)
      af[mi] = *(const bf16x8*)&As[cur][(wr * 64 + mi * 16 + l15) * 32 + ((lh * 8) ^ bxor)];
    #pragma unroll
    for (int ni = 0; ni < 4; ++ni)
      bfr[ni] = *(const bf16x8*)&Bs[cur][(wc * 64 + ni * 16 + l15) * 32 + ((lh * 8) ^ bxor)];
    #pragma unroll
    for (int mi = 0; mi < 4; ++mi)
      #pragma unroll
      for (int ni = 0; ni < 4; ++ni)
        acc[mi][ni] = mfma16(af[mi], bfr[ni], acc[mi][ni]);
    asm volatile("s_waitcnt vmcnt(0)");
    __syncthreads();
    cur = nxt;
  }

  #pragma unroll
  for (int ni = 0; ni < 4; ++ni) {
    const int e = col0 + wc * 64 + ni * 16 + l15;
    const float bia = bias[e];
    #pragma unroll
    for (int mi = 0; mi < 4; ++mi) {
      #pragma unroll
      for (int r = 0; r < 4; ++r) {
        const int row = row0 + wr * 64 + mi * 16 + lh * 4 + r;
        out[(size_t)row * 768 + e] = acc[mi][ni][r] + bia;
      }
    }
  }
}

extern "C" void kernel_launch(void* const* d_in, const int* in_sizes, int n_in,
                              void* d_out, int out_size, void* d_ws, size_t ws_size,
                              hipStream_t stream) {
  const float* query = (const float*)d_in[0];
  const float* key_  = (const float*)d_in[1];
  const float* value = (const float*)d_in[2];
  const float* Wq = (const float*)d_in[3];
  const float* bq = (const float*)d_in[4];
  const float* Wk = (const float*)d_in[5];
  const float* bk = (const float*)d_in[6];
  const float* Wv = (const float*)d_in[7];
  const float* bv = (const float*)d_in[8];
  const float* Wo = (const float*)d_in[9];
  const float* bo = (const float*)d_in[10];
  const float* lng = (const float*)d_in[11];
  const float* lnb = (const float*)d_in[12];

  char* ws = (char*)d_ws;
  size_t off = 0;
  auto alloc = [&](size_t bytes) { size_t o = off; off += (bytes + 255) & ~(size_t)255; return o; };
  const size_t WB = 768 * 768 * 2;            // bf16 weight bytes
  const size_t GB = (size_t)56 * ISTR * 2;    // gathered bf16 bytes (14.68 MB)
  const size_t XB = (size_t)16384 * 768 * 2;  // bf16 X bytes (25.17 MB)
  const size_t OPB = (size_t)2 * 56 * 2048 * 32 * 4;  // 58.72 MB
  const size_t LSB = (size_t)2 * 56 * 2048 * 4;       // 0.92 MB

  u16* wqb = (u16*)(ws + alloc(WB));
  u16* wkb = (u16*)(ws + alloc(WB));
  u16* wvb = (u16*)(ws + alloc(WB));
  u16* wob = (u16*)(ws + alloc(WB));
  u16* Qg  = (u16*)(ws + alloc(GB));
  u16* Kg  = (u16*)(ws + alloc(GB));
  u16* VgT = (u16*)(ws + alloc(GB));

  // Overlaid region: Xb16 (3*XB) lifetime = [cvt_x, qkv_fused];
  // Op32+Lsb+xln lifetime = [dil_attn, out_gemm] — strictly after Xb16 is dead.
  const size_t regionSz = ((3 * XB > OPB + LSB + 256 * 2 + XB) ? 3 * XB : OPB + LSB + 256 * 2 + XB) + 1024;
  char* region = ws + alloc(regionSz);
  u16* Xq = (u16*)(region);
  u16* Xk = (u16*)(region + XB);
  u16* Xv = (u16*)(region + 2 * XB);
  uint32* Op32 = (uint32*)(region);
  float*  Lsb  = (float*)(region + ((OPB + 255) & ~(size_t)255));
  u16*    xln  = (u16*)(region + ((OPB + 255) & ~(size_t)255) + ((LSB + 255) & ~(size_t)255));

  const int n4 = 768 * 768 / 4;
  cvt_w4<<<dim3(576, 4), 256, 0, stream>>>(Wq, Wk, Wv, Wo, wqb, wkb, wvb, wob, n4);
  cvt_x<<<dim3(1536, 3), 256, 0, stream>>>(query, key_, value, Xq, Xk, Xv);

  qkv_fused<<<dim3(128, 18), 256, 0, stream>>>(
      Xq, Xk, Xv, wqb, wkb, wvb, bq, bk, bv, Qg, Kg, VgT);

  dil_attn<<<dim3(1792), 256, 0, stream>>>(Qg, Kg, VgT, Op32, Lsb);
  ln_gather<<<dim3(16384), 256, 0, stream>>>(Op32, Lsb, lng, lnb, xln);
  out_gemm<<<dim3(128, 6), 256, 0, stream>>>(xln, wob, bo, (float*)d_out);
}